// Round 1
// baseline (280.093 us; speedup 1.0000x reference)
//
#include <hip/hip_runtime.h>
#include <hip/hip_fp16.h>
#include <math.h>

#define HW 240
#define PITCH 241          // +1 complex pad on LDS rows
#define IMG_PIX (HW*HW)    // 57600
#define NB 15              // kw blocks per image
#define TILE_ELEMS (240*16) // 3840 elements per blocked chunk

__device__ __forceinline__ float2 cmul(float2 a, float2 b){
    return make_float2(a.x*b.x - a.y*b.y, a.x*b.y + a.y*b.x);
}
__device__ __forceinline__ float2 cadd(float2 a, float2 b){
    return make_float2(a.x+b.x, a.y+b.y);
}
__device__ __forceinline__ float2 csub(float2 a, float2 b){
    return make_float2(a.x-b.x, a.y-b.y);
}
__device__ __forceinline__ __half2 f2h(float2 a){ return __floats2half2_rn(a.x, a.y); }
__device__ __forceinline__ float2 h2f(__half2 h){ return make_float2(__low2float(h), __high2float(h)); }

// ---------- 15-point DFT via Cooley-Tukey 3x5, all-constant twiddles ----------
template<int SIGN>
__device__ __forceinline__ void dft15(const float2* x, float2* X){
    const float S = (float)SIGN;
    const float s3 = 0.8660254037844387f;
    float2 y[5][3];
    #pragma unroll
    for (int n2 = 0; n2 < 5; ++n2){
        float2 a0 = x[n2], a1 = x[5+n2], a2 = x[10+n2];
        float2 t = cadd(a1, a2);
        float2 u = csub(a1, a2);
        float2 m = make_float2(a0.x - 0.5f*t.x, a0.y - 0.5f*t.y);
        float sx = S * s3;
        float2 s = make_float2(-sx*u.y, sx*u.x);
        y[n2][0] = cadd(a0, t);
        y[n2][1] = cadd(m, s);
        y[n2][2] = csub(m, s);
    }
    const float C15[9] = {1.f, 0.9135454576426009f, 0.6691306063588582f, 0.30901699437494745f,
                          -0.10452846326765346f, -0.5f, -0.8090169943749475f,
                          -0.9781476007338057f, -0.9781476007338057f};
    const float S15[9] = {0.f, 0.4067366430758004f, 0.7431448254773942f, 0.9510565162951535f,
                          0.9945218953682733f, 0.8660254037844387f, 0.5877852522924731f,
                          0.20791169081775931f, -0.20791169081775931f};
    #pragma unroll
    for (int n2 = 1; n2 < 5; ++n2){
        #pragma unroll
        for (int k1 = 1; k1 < 3; ++k1){
            const int e = n2*k1;
            y[n2][k1] = cmul(y[n2][k1], make_float2(C15[e], S*S15[e]));
        }
    }
    const float c1 = 0.30901699437494745f, s1 = 0.9510565162951535f;
    const float c2 = -0.8090169943749475f, s2 = 0.5877852522924731f;
    #pragma unroll
    for (int k1 = 0; k1 < 3; ++k1){
        float2 x0 = y[0][k1], x1 = y[1][k1], x2 = y[2][k1], x3 = y[3][k1], x4 = y[4][k1];
        float2 t1 = cadd(x1, x4), t3 = csub(x1, x4);
        float2 t2 = cadd(x2, x3), t4 = csub(x2, x3);
        X[k1] = make_float2(x0.x + t1.x + t2.x, x0.y + t1.y + t2.y);
        float2 u1 = make_float2(x0.x + c1*t1.x + c2*t2.x, x0.y + c1*t1.y + c2*t2.y);
        float2 u2 = make_float2(x0.x + c2*t1.x + c1*t2.x, x0.y + c2*t1.y + c1*t2.y);
        float2 v1 = make_float2(S*(s1*t3.x + s2*t4.x), S*(s1*t3.y + s2*t4.y));
        float2 v2 = make_float2(S*(s2*t3.x - s1*t4.x), S*(s2*t3.y - s1*t4.y));
        X[k1+3]  = make_float2(u1.x - v1.y, u1.y + v1.x);
        X[k1+12] = make_float2(u1.x + v1.y, u1.y - v1.x);
        X[k1+6]  = make_float2(u2.x - v2.y, u2.y + v2.x);
        X[k1+9]  = make_float2(u2.x + v2.y, u2.y - v2.x);
    }
}

// ---------- 16-point DFT via radix-4 x radix-4, all-constant twiddles ----------
template<int SIGN>
__device__ __forceinline__ void dft16(const float2* x, float2* X){
    const float S = (float)SIGN;
    float2 y[4][4];
    #pragma unroll
    for (int n2 = 0; n2 < 4; ++n2){
        float2 a0 = x[n2], a1 = x[4+n2], a2 = x[8+n2], a3 = x[12+n2];
        float2 t0 = cadd(a0,a2), t1 = csub(a0,a2);
        float2 t2 = cadd(a1,a3), t3 = csub(a1,a3);
        float2 it3 = make_float2(-S*t3.y, S*t3.x);
        y[n2][0] = cadd(t0,t2);
        y[n2][2] = csub(t0,t2);
        y[n2][1] = cadd(t1,it3);
        y[n2][3] = csub(t1,it3);
    }
    const float C16[10] = {1.f, 0.9238795325112867f, 0.7071067811865476f, 0.3826834323650898f,
                           0.f, -0.3826834323650898f, -0.7071067811865476f, -0.9238795325112867f,
                           -1.f, -0.9238795325112867f};
    const float S16[10] = {0.f, 0.3826834323650898f, 0.7071067811865476f, 0.9238795325112867f,
                           1.f, 0.9238795325112867f, 0.7071067811865476f, 0.3826834323650898f,
                           0.f, -0.3826834323650898f};
    #pragma unroll
    for (int n2 = 1; n2 < 4; ++n2){
        #pragma unroll
        for (int k1 = 1; k1 < 4; ++k1){
            const int e = n2*k1;
            y[n2][k1] = cmul(y[n2][k1], make_float2(C16[e], S*S16[e]));
        }
    }
    #pragma unroll
    for (int k1 = 0; k1 < 4; ++k1){
        float2 a0 = y[0][k1], a1 = y[1][k1], a2 = y[2][k1], a3 = y[3][k1];
        float2 t0 = cadd(a0,a2), t1 = csub(a0,a2);
        float2 t2 = cadd(a1,a3), t3 = csub(a1,a3);
        float2 it3 = make_float2(-S*t3.y, S*t3.x);
        X[k1]    = cadd(t0,t2);
        X[k1+8]  = csub(t0,t2);
        X[k1+4]  = cadd(t1,it3);
        X[k1+12] = csub(t1,it3);
    }
}

// Cooperative 240-point FFT for 16 rows at once. v[a] = x[16a+b] preloaded.
// On return sm[rl][k] = X[k]. 3 internal barriers.
template<int SIGN>
__device__ void fft240(float2 (*sm)[PITCH], float2* v, int rl, int b){
    const float TWOPI = 6.28318530717958647692f;
    float2 Y[15];
    dft15<SIGN>(v, Y);
    float2 step, tw = make_float2(1.0f, 0.0f);
    {
        float ang = (float)SIGN * TWOPI * (float)b * (1.0f/240.0f);
        __sincosf(ang, &step.y, &step.x);
    }
    #pragma unroll
    for (int d = 0; d < 15; ++d){
        sm[rl][b*15 + d] = cmul(Y[d], tw);
        tw = cmul(tw, step);
    }
    __syncthreads();

    float2 Z[16];
    if (b < 15){
        #pragma unroll
        for (int bb = 0; bb < 16; ++bb) Z[bb] = sm[rl][bb*15 + b];
    }
    __syncthreads();
    if (b < 15){
        float2 XX[16];
        dft16<SIGN>(Z, XX);
        #pragma unroll
        for (int m = 0; m < 16; ++m) sm[rl][15*m + b] = XX[m];
    }
    __syncthreads();
}

// Pass A: flat-load 16 rows of real x -> LDS; row FFT; store fp16 blocked:
// inter[((img*15+kb)*240 + h)*16 + kwin],  kw = kb*16+kwin
__global__ __launch_bounds__(256) void passA_rowfft(const float* __restrict__ x,
                                                    __half2* __restrict__ out){
    __shared__ float2 sm[16][PITCH];
    float* smf = (float*)sm;                 // float pitch = 2*PITCH = 482
    int g = blockIdx.x, img = g / NB, h0 = (g % NB) * 16;
    int tid = threadIdx.x, rl = tid >> 4, b = tid & 15;
    const float* src = x + (size_t)img * IMG_PIX + (size_t)h0 * HW;
    #pragma unroll
    for (int j = 0; j < 15; ++j){
        int f = j*256 + tid;
        smf[(f/HW)*(2*PITCH) + (f%HW)] = src[f];   // contiguous 1 KB / wave-instr
    }
    __syncthreads();
    float2 v[15];
    #pragma unroll
    for (int a = 0; a < 15; ++a) v[a] = make_float2(smf[rl*(2*PITCH) + 16*a + b], 0.0f);
    __syncthreads();                          // all gathers done before fft scribbles sm
    fft240<-1>(sm, v, rl, b);                 // sm[r][kw], r = local h
    int hl = rl, kwin = b;
    #pragma unroll
    for (int kb = 0; kb < NB; ++kb){
        float2 val = sm[hl][kb*16 + kwin];
        out[((size_t)(img*NB + kb)*HW + h0 + hl)*16 + kwin] = f2h(val);
    }
}

// Pass B (IN-PLACE): each block owns exactly one blocked chunk (16 kw cols x 240 h).
// Load whole chunk -> LDS (barrier) -> col FFT -> combine with y_k -> inverse col
// FFT (x 1/240) -> store the SAME chunk. Chunk-local => no cross-block hazard,
// and all loads complete (barriered) before the first store.
__global__ __launch_bounds__(256) void passB_col_dc_icol(__half2* __restrict__ io,
                                                         const float* __restrict__ under,
                                                         const float* __restrict__ Am){
    __shared__ float2 sm[16][PITCH];
    int g = blockIdx.x, img = g / NB, s = g % NB, kw0 = s * 16;
    int tid = threadIdx.x, rl = tid >> 4, b = tid & 15;
    __half2* chunk = io + (size_t)(img*NB + s) * TILE_ELEMS;   // [h][c]
    #pragma unroll
    for (int j = 0; j < 15; ++j){
        int f = j*256 + tid;
        sm[f & 15][f >> 4] = h2f(chunk[f]);   // contiguous 256B / wave-instr
    }
    __syncthreads();
    float2 v[15];
    #pragma unroll
    for (int a = 0; a < 15; ++a) v[a] = sm[rl][16*a + b];
    __syncthreads();
    fft240<-1>(sm, v, rl, b);                 // sm[c][kh]

    const float* y0 = under + (size_t)img * (2*IMG_PIX);
    const float* y1 = y0 + IMG_PIX;
    #pragma unroll
    for (int j = 0; j < 15; ++j){
        int kh = j*16 + rl;
        size_t p = (size_t)kh * HW + kw0 + b;
        float sc = 1.0f - Am[p];
        float2 X = sm[b][kh];
        sm[b][kh] = make_float2(sc * X.x + y0[p], sc * X.y + y1[p]);
    }
    __syncthreads();
    #pragma unroll
    for (int a = 0; a < 15; ++a) v[a] = sm[rl][16*a + b];
    __syncthreads();
    fft240<+1>(sm, v, rl, b);                 // sm[c][h]

    const float inv240 = 1.0f / 240.0f;
    #pragma unroll
    for (int j = 0; j < 15; ++j){
        int f = j*256 + tid;
        float2 val = sm[f & 15][f >> 4];
        val.x *= inv240; val.y *= inv240;
        chunk[f] = f2h(val);
    }
}

// Pass C: gather 15 blocked chunks (each contiguous 1KB) -> row tile [16 h][240 kw];
// inverse row FFT; abs * 1/240; flat store natural out.
__global__ __launch_bounds__(256) void passC_irow_abs(const __half2* __restrict__ in,
                                                      float* __restrict__ outp){
    __shared__ float2 sm[16][PITCH];
    int g = blockIdx.x, img = g / NB, h0 = (g % NB) * 16;
    int tid = threadIdx.x, rl = tid >> 4, b = tid & 15;
    int hl = rl, kwin = b;
    #pragma unroll
    for (int kb = 0; kb < NB; ++kb){
        __half2 hv = in[((size_t)(img*NB + kb)*HW + h0 + hl)*16 + kwin];
        sm[hl][kb*16 + kwin] = h2f(hv);
    }
    __syncthreads();
    float2 v[15];
    #pragma unroll
    for (int a = 0; a < 15; ++a) v[a] = sm[rl][16*a + b];
    __syncthreads();
    fft240<+1>(sm, v, rl, b);                 // sm[r][w]
    float* dst = outp + (size_t)img * IMG_PIX + (size_t)h0 * HW;
    const float inv240 = 1.0f / 240.0f;
    #pragma unroll
    for (int j = 0; j < 15; ++j){
        int f = j*256 + tid;
        float2 X = sm[f/HW][f%HW];
        dst[f] = sqrtf(X.x*X.x + X.y*X.y) * inv240;
    }
}

extern "C" void kernel_launch(void* const* d_in, const int* in_sizes, int n_in,
                              void* d_out, int out_size, void* d_ws, size_t ws_size,
                              hipStream_t stream){
    const float* T2   = (const float*)d_in[0];   // [256,1,240,240] f32
    const float* U    = (const float*)d_in[1];   // [256,2,240,240] f32
    const float* Am   = (const float*)d_in[2];   // [240,240] f32
    float* out        = (float*)d_out;           // [256,1,240,240] f32

    const int B = 256;
    // Single 59 MB fp16 intermediate; passB runs fully in place on it.
    __half2* i1 = (__half2*)d_ws;                // B*57600 half2 = 59 MB total

    dim3 grid(B * NB), block(256);
    passA_rowfft     <<<grid, block, 0, stream>>>(T2, i1);
    passB_col_dc_icol<<<grid, block, 0, stream>>>(i1, U, Am);
    passC_irow_abs   <<<grid, block, 0, stream>>>(i1, out);
}

// Round 2
// 274.190 us; speedup vs baseline: 1.0215x; 1.0215x over previous
//
#include <hip/hip_runtime.h>
#include <hip/hip_fp16.h>
#include <math.h>

#define HW 240
#define PITCH 242          // +2 complex pad: keeps float4 LDS rows 16B-aligned
#define SMF_PITCH (2*PITCH) // 484 floats
#define IMG_PIX (HW*HW)    // 57600
#define NB 15              // kw blocks per image
#define TILE_ELEMS (240*16) // 3840 elements per blocked chunk

__device__ __forceinline__ float2 cmul(float2 a, float2 b){
    return make_float2(a.x*b.x - a.y*b.y, a.x*b.y + a.y*b.x);
}
__device__ __forceinline__ float2 cadd(float2 a, float2 b){
    return make_float2(a.x+b.x, a.y+b.y);
}
__device__ __forceinline__ float2 csub(float2 a, float2 b){
    return make_float2(a.x-b.x, a.y-b.y);
}
__device__ __forceinline__ __half2 f2h(float2 a){ return __floats2half2_rn(a.x, a.y); }
__device__ __forceinline__ float2 h2f(__half2 h){ return make_float2(__low2float(h), __high2float(h)); }

// Compiler-only fence: LDS ops within a wave execute in issue order on the DS
// pipe, so intra-wave exchanges need no s_barrier — only a scheduling fence.
__device__ __forceinline__ void wave_fence(){ __builtin_amdgcn_wave_barrier(); }

// ---------- 15-point DFT via Cooley-Tukey 3x5, all-constant twiddles ----------
template<int SIGN>
__device__ __forceinline__ void dft15(const float2* x, float2* X){
    const float S = (float)SIGN;
    const float s3 = 0.8660254037844387f;
    float2 y[5][3];
    #pragma unroll
    for (int n2 = 0; n2 < 5; ++n2){
        float2 a0 = x[n2], a1 = x[5+n2], a2 = x[10+n2];
        float2 t = cadd(a1, a2);
        float2 u = csub(a1, a2);
        float2 m = make_float2(a0.x - 0.5f*t.x, a0.y - 0.5f*t.y);
        float sx = S * s3;
        float2 s = make_float2(-sx*u.y, sx*u.x);
        y[n2][0] = cadd(a0, t);
        y[n2][1] = cadd(m, s);
        y[n2][2] = csub(m, s);
    }
    const float C15[9] = {1.f, 0.9135454576426009f, 0.6691306063588582f, 0.30901699437494745f,
                          -0.10452846326765346f, -0.5f, -0.8090169943749475f,
                          -0.9781476007338057f, -0.9781476007338057f};
    const float S15[9] = {0.f, 0.4067366430758004f, 0.7431448254773942f, 0.9510565162951535f,
                          0.9945218953682733f, 0.8660254037844387f, 0.5877852522924731f,
                          0.20791169081775931f, -0.20791169081775931f};
    #pragma unroll
    for (int n2 = 1; n2 < 5; ++n2){
        #pragma unroll
        for (int k1 = 1; k1 < 3; ++k1){
            const int e = n2*k1;
            y[n2][k1] = cmul(y[n2][k1], make_float2(C15[e], S*S15[e]));
        }
    }
    const float c1 = 0.30901699437494745f, s1 = 0.9510565162951535f;
    const float c2 = -0.8090169943749475f, s2 = 0.5877852522924731f;
    #pragma unroll
    for (int k1 = 0; k1 < 3; ++k1){
        float2 x0 = y[0][k1], x1 = y[1][k1], x2 = y[2][k1], x3 = y[3][k1], x4 = y[4][k1];
        float2 t1 = cadd(x1, x4), t3 = csub(x1, x4);
        float2 t2 = cadd(x2, x3), t4 = csub(x2, x3);
        X[k1] = make_float2(x0.x + t1.x + t2.x, x0.y + t1.y + t2.y);
        float2 u1 = make_float2(x0.x + c1*t1.x + c2*t2.x, x0.y + c1*t1.y + c2*t2.y);
        float2 u2 = make_float2(x0.x + c2*t1.x + c1*t2.x, x0.y + c2*t1.y + c1*t2.y);
        float2 v1 = make_float2(S*(s1*t3.x + s2*t4.x), S*(s1*t3.y + s2*t4.y));
        float2 v2 = make_float2(S*(s2*t3.x - s1*t4.x), S*(s2*t3.y - s1*t4.y));
        X[k1+3]  = make_float2(u1.x - v1.y, u1.y + v1.x);
        X[k1+12] = make_float2(u1.x + v1.y, u1.y - v1.x);
        X[k1+6]  = make_float2(u2.x - v2.y, u2.y + v2.x);
        X[k1+9]  = make_float2(u2.x + v2.y, u2.y - v2.x);
    }
}

// ---------- 16-point DFT via radix-4 x radix-4, all-constant twiddles ----------
template<int SIGN>
__device__ __forceinline__ void dft16(const float2* x, float2* X){
    const float S = (float)SIGN;
    float2 y[4][4];
    #pragma unroll
    for (int n2 = 0; n2 < 4; ++n2){
        float2 a0 = x[n2], a1 = x[4+n2], a2 = x[8+n2], a3 = x[12+n2];
        float2 t0 = cadd(a0,a2), t1 = csub(a0,a2);
        float2 t2 = cadd(a1,a3), t3 = csub(a1,a3);
        float2 it3 = make_float2(-S*t3.y, S*t3.x);
        y[n2][0] = cadd(t0,t2);
        y[n2][2] = csub(t0,t2);
        y[n2][1] = cadd(t1,it3);
        y[n2][3] = csub(t1,it3);
    }
    const float C16[10] = {1.f, 0.9238795325112867f, 0.7071067811865476f, 0.3826834323650898f,
                           0.f, -0.3826834323650898f, -0.7071067811865476f, -0.9238795325112867f,
                           -1.f, -0.9238795325112867f};
    const float S16[10] = {0.f, 0.3826834323650898f, 0.7071067811865476f, 0.9238795325112867f,
                           1.f, 0.9238795325112867f, 0.7071067811865476f, 0.3826834323650898f,
                           0.f, -0.3826834323650898f};
    #pragma unroll
    for (int n2 = 1; n2 < 4; ++n2){
        #pragma unroll
        for (int k1 = 1; k1 < 4; ++k1){
            const int e = n2*k1;
            y[n2][k1] = cmul(y[n2][k1], make_float2(C16[e], S*S16[e]));
        }
    }
    #pragma unroll
    for (int k1 = 0; k1 < 4; ++k1){
        float2 a0 = y[0][k1], a1 = y[1][k1], a2 = y[2][k1], a3 = y[3][k1];
        float2 t0 = cadd(a0,a2), t1 = csub(a0,a2);
        float2 t2 = cadd(a1,a3), t3 = csub(a1,a3);
        float2 it3 = make_float2(-S*t3.y, S*t3.x);
        X[k1]    = cadd(t0,t2);
        X[k1+8]  = csub(t0,t2);
        X[k1+4]  = cadd(t1,it3);
        X[k1+12] = csub(t1,it3);
    }
}

// Cooperative 240-point FFT for 16 rows. v[a] = x[16a+b] preloaded.
// On return sm[rl][k] = X[k]. ALL exchanges are within row rl, and a row's 16
// lanes live in one wave (4 rows/wave) -> ZERO block barriers; DS-pipe order +
// wave_fence() give correctness.
template<int SIGN>
__device__ void fft240(float2 (*sm)[PITCH], float2* v, int rl, int b){
    const float TWOPI = 6.28318530717958647692f;
    float2 Y[15];
    dft15<SIGN>(v, Y);
    float2 step, tw = make_float2(1.0f, 0.0f);
    {
        float ang = (float)SIGN * TWOPI * (float)b * (1.0f/240.0f);
        __sincosf(ang, &step.y, &step.x);
    }
    #pragma unroll
    for (int d = 0; d < 15; ++d){
        sm[rl][b*15 + d] = cmul(Y[d], tw);
        tw = cmul(tw, step);
    }
    wave_fence();
    float2 Z[16];
    if (b < 15){
        #pragma unroll
        for (int bb = 0; bb < 16; ++bb) Z[bb] = sm[rl][bb*15 + b];
    }
    wave_fence();
    if (b < 15){
        float2 XX[16];
        dft16<SIGN>(Z, XX);
        #pragma unroll
        for (int m = 0; m < 16; ++m) sm[rl][15*m + b] = XX[m];
    }
    wave_fence();
}

// Pass A: float4-load 16 rows of real x -> LDS; row FFT; store fp16 blocked:
// inter[((img*15+kb)*240 + h)*16 + kwin],  kw = kb*16+kwin. ONE block barrier.
__global__ __launch_bounds__(256) void passA_rowfft(const float* __restrict__ x,
                                                    __half2* __restrict__ out){
    __shared__ __align__(16) float2 sm[16][PITCH];
    float* smf = (float*)sm;                 // float pitch = 484 (16B-aligned rows)
    int g = blockIdx.x, img = g / NB, h0 = (g % NB) * 16;
    int tid = threadIdx.x, rl = tid >> 4, b = tid & 15;
    const float* src = x + (size_t)img * IMG_PIX + (size_t)h0 * HW;
    if (tid < 240){
        #pragma unroll
        for (int jj = 0; jj < 4; ++jj){
            int k = jj*240 + tid;            // k in [0,960)
            int r = k / 60, c = 4*(k - r*60);
            float4 d = *(const float4*)(src + 4*k);   // 1 KB per 16 lanes
            *(float4*)(smf + r*SMF_PITCH + c) = d;
        }
    }
    __syncthreads();                          // stage scatter is cross-wave
    float2 v[15];
    #pragma unroll
    for (int a = 0; a < 15; ++a) v[a] = make_float2(smf[rl*SMF_PITCH + 16*a + b], 0.0f);
    wave_fence();                             // fft overwrites own-wave rows only
    fft240<-1>(sm, v, rl, b);                 // sm[r][kw], r = local h
    #pragma unroll
    for (int kb = 0; kb < NB; ++kb){          // reads own row rl: no barrier
        float2 val = sm[rl][kb*16 + b];
        out[((size_t)(img*NB + kb)*HW + h0 + rl)*16 + b] = f2h(val);
    }
}

// Pass B (IN-PLACE): one blocked chunk (16 kw cols x 240 h) per block.
// float4 stage -> col FFT -> DC combine -> inverse col FFT -> float4 store.
// FOUR block barriers (stage scatter, around the cross-row DC combine, store).
__global__ __launch_bounds__(256) void passB_col_dc_icol(__half2* __restrict__ io,
                                                         const float* __restrict__ under,
                                                         const float* __restrict__ Am){
    __shared__ __align__(16) float2 sm[16][PITCH];
    int g = blockIdx.x, img = g / NB, s = g % NB, kw0 = s * 16;
    int tid = threadIdx.x, rl = tid >> 4, b = tid & 15;
    __half2* chunk = io + (size_t)(img*NB + s) * TILE_ELEMS;   // [h][c]
    if (tid < 240){
        #pragma unroll
        for (int jj = 0; jj < 4; ++jj){
            int k = jj*240 + tid;             // element f = 4k
            float4 raw = *(const float4*)(chunk + 4*k);   // 4 half2 = 16 B
            const __half2* hp = (const __half2*)&raw;
            int col = k >> 2;                 // (4k)>>4, same for all 4
            int r0 = (4*k) & 15;              // rows r0..r0+3
            #pragma unroll
            for (int i = 0; i < 4; ++i) sm[r0 + i][col] = h2f(hp[i]);
        }
    }
    __syncthreads();                          // B1: cross-wave scatter
    float2 v[15];
    #pragma unroll
    for (int a = 0; a < 15; ++a) v[a] = sm[rl][16*a + b];
    wave_fence();
    fft240<-1>(sm, v, rl, b);                 // sm[c][kh]
    __syncthreads();                          // B2: combine reads cross-wave rows

    const float* y0 = under + (size_t)img * (2*IMG_PIX);
    const float* y1 = y0 + IMG_PIX;
    #pragma unroll
    for (int j = 0; j < 15; ++j){
        int kh = j*16 + rl;
        size_t p = (size_t)kh * HW + kw0 + b;
        float sc = 1.0f - Am[p];
        float2 X = sm[b][kh];
        sm[b][kh] = make_float2(sc * X.x + y0[p], sc * X.y + y1[p]);
    }
    __syncthreads();                          // B3: combine wrote cross-wave rows
    #pragma unroll
    for (int a = 0; a < 15; ++a) v[a] = sm[rl][16*a + b];
    wave_fence();
    fft240<+1>(sm, v, rl, b);                 // sm[c][h]
    __syncthreads();                          // B4: store reads cross-wave rows

    const float inv240 = 1.0f / 240.0f;
    if (tid < 240){
        #pragma unroll
        for (int jj = 0; jj < 4; ++jj){
            int k = jj*240 + tid;
            int col = k >> 2;
            int r0 = (4*k) & 15;
            float4 outv;
            __half2* op = (__half2*)&outv;
            #pragma unroll
            for (int i = 0; i < 4; ++i){
                float2 val = sm[r0 + i][col];
                op[i] = f2h(make_float2(val.x*inv240, val.y*inv240));
            }
            *(float4*)(chunk + 4*k) = outv;   // 16 B/lane contiguous
        }
    }
}

// Pass C: gather 15 blocked chunks -> row tile [16 h][240 kw] (own-wave rows:
// no stage barrier); inverse row FFT; abs * 1/240; float4 flat store. ONE barrier.
__global__ __launch_bounds__(256) void passC_irow_abs(const __half2* __restrict__ in,
                                                      float* __restrict__ outp){
    __shared__ __align__(16) float2 sm[16][PITCH];
    int g = blockIdx.x, img = g / NB, h0 = (g % NB) * 16;
    int tid = threadIdx.x, rl = tid >> 4, b = tid & 15;
    #pragma unroll
    for (int kb = 0; kb < NB; ++kb){
        __half2 hv = in[((size_t)(img*NB + kb)*HW + h0 + rl)*16 + b];
        sm[rl][kb*16 + b] = h2f(hv);          // own row: intra-wave only
    }
    wave_fence();
    float2 v[15];
    #pragma unroll
    for (int a = 0; a < 15; ++a) v[a] = sm[rl][16*a + b];
    wave_fence();
    fft240<+1>(sm, v, rl, b);                 // sm[r][w]
    __syncthreads();                          // final store reads cross-wave rows
    float* dst = outp + (size_t)img * IMG_PIX + (size_t)h0 * HW;
    const float inv240 = 1.0f / 240.0f;
    if (tid < 240){
        #pragma unroll
        for (int jj = 0; jj < 4; ++jj){
            int k = jj*240 + tid;
            int r = k / 60, c = 4*(k - r*60);
            float4 o;
            float2 X0 = sm[r][c+0], X1 = sm[r][c+1], X2 = sm[r][c+2], X3 = sm[r][c+3];
            o.x = sqrtf(X0.x*X0.x + X0.y*X0.y) * inv240;
            o.y = sqrtf(X1.x*X1.x + X1.y*X1.y) * inv240;
            o.z = sqrtf(X2.x*X2.x + X2.y*X2.y) * inv240;
            o.w = sqrtf(X3.x*X3.x + X3.y*X3.y) * inv240;
            *(float4*)(dst + 4*k) = o;        // 16 B/lane contiguous
        }
    }
}

extern "C" void kernel_launch(void* const* d_in, const int* in_sizes, int n_in,
                              void* d_out, int out_size, void* d_ws, size_t ws_size,
                              hipStream_t stream){
    const float* T2   = (const float*)d_in[0];   // [256,1,240,240] f32
    const float* U    = (const float*)d_in[1];   // [256,2,240,240] f32
    const float* Am   = (const float*)d_in[2];   // [240,240] f32
    float* out        = (float*)d_out;           // [256,1,240,240] f32

    const int B = 256;
    // Single 59 MB fp16 intermediate; passB runs fully in place on it.
    __half2* i1 = (__half2*)d_ws;                // B*57600 half2

    dim3 grid(B * NB), block(256);
    passA_rowfft     <<<grid, block, 0, stream>>>(T2, i1);
    passB_col_dc_icol<<<grid, block, 0, stream>>>(i1, U, Am);
    passC_irow_abs   <<<grid, block, 0, stream>>>(i1, out);
}